// Round 11
// baseline (534.830 us; speedup 1.0000x reference)
//
#include <hip/hip_runtime.h>

#define HW 4096
#define CC 256
#define KK 2048
#define BB 16
#define NN (BB*HW)          // 65536
#define RPB 128             // rows per block

// d_out layout (floats): [z_q 16777216][idx 65536][loss 1][probs 134217728]
#define ZQ_SZ   (BB*CC*HW)
#define IDX_OFF ZQ_SZ
#define LOSS_OFF (IDX_OFF + NN)
#define PROBS_OFF (LOSS_OFF + 1)

// scratch parked in z_q region (float offsets), overwritten by k_zq at the end
#define EH_OFF 0          // eh[K][C] bf16 (rn) = 262144 floats
#define EE_OFF 262144     // ee_np[K] f32
#define EXT_OFF 264192    // eext[K][16] bf16 = 16384 floats (ee-channel block)
#define ZZ_OFF 280576     // zz_np[N] f32

#define TAU 0.01f
#define CAND_CAP 512
#define KTC 32            // codes per k-tile
#define KT_N 64           // tiles per pass
#define CS_N 17           // 16 real c-slices + 1 ee-slice

typedef short bf16x8 __attribute__((ext_vector_type(8)));
typedef float f32x16 __attribute__((ext_vector_type(16)));
typedef unsigned int u32;

__device__ __forceinline__ void gload16(const void* g, void* l){
  __builtin_amdgcn_global_load_lds(
      (const __attribute__((address_space(1))) u32*)g,
      (__attribute__((address_space(3))) u32*)l, 16, 0, 0);
}

__device__ __forceinline__ unsigned short bf16rn(float x){
  unsigned u = __float_as_uint(x);
  return (unsigned short)((u + 0x7fffu + ((u >> 16) & 1u)) >> 16);
}

// ---- numpy pairwise sum-of-squares over 256 elems (PW_BLOCKSIZE=128) ----
template<int STRIDE>
__device__ __forceinline__ float np_sumsq256(const float* __restrict__ a){
  float res0 = 0.f, res1 = 0.f;
  #pragma unroll
  for (int h = 0; h < 2; h++){
    const float* p = a + (size_t)h * 128 * STRIDE;
    float r[8];
    #pragma unroll
    for (int j = 0; j < 8; j++){ float x = p[(size_t)j * STRIDE]; r[j] = __fmul_rn(x, x); }
    for (int i = 8; i < 128; i += 8){
      #pragma unroll
      for (int j = 0; j < 8; j++){
        float x = p[(size_t)(i + j) * STRIDE];
        r[j] = __fadd_rn(r[j], __fmul_rn(x, x));
      }
    }
    float s = __fadd_rn(__fadd_rn(__fadd_rn(r[0], r[1]), __fadd_rn(r[2], r[3])),
                        __fadd_rn(__fadd_rn(r[4], r[5]), __fadd_rn(r[6], r[7])));
    if (h == 0) res0 = s; else res1 = s;
  }
  return __fadd_rn(res0, res1);
}

// ---------------- prep: bf16(rn) codebook + np-exact ee + ee-channel ----------------
__global__ void k_prep2(const float* __restrict__ cb, float* __restrict__ out){
  const int k = blockIdx.x * 256 + threadIdx.x;   // 8 blocks
  unsigned short* eh = (unsigned short*)(out + EH_OFF);
  unsigned short* ex = (unsigned short*)(out + EXT_OFF);
  const float* row = cb + (size_t)k * CC;
  for (int c = 0; c < CC; c++) eh[k * CC + c] = bf16rn(row[c]);
  float ee = np_sumsq256<1>(row);
  out[EE_OFF + k] = ee;
  ex[k * 16] = bf16rn(-0.5f * ee);
  #pragma unroll
  for (int j = 1; j < 16; ++j) ex[k * 16 + j] = 0;
}

// ---------------- zz[n] = np-pairwise sum_c feats^2 ----------------
__global__ void k_zz(const float* __restrict__ feats, float* __restrict__ out){
  const int n = blockIdx.x * 256 + threadIdx.x;   // 256 blocks
  const int b = n >> 12, hw = n & 4095;
  out[ZZ_OFF + n] = np_sumsq256<HW>(feats + (size_t)b * CC * HW + hw);
}

// ---------------- main MFMA kernel: 128 rows x 2048 codes, 4 waves, 512 blocks ----------------
// lds_e[buf][cs 17][grp 2][code 32][16B]; mfma(e, z) -> D[code][zrow]; s = -2*acc
__global__ __launch_bounds__(256, 4)
void k_mfma(const float* __restrict__ feats, const float* __restrict__ cb,
            float* __restrict__ out){
  __shared__ __align__(16) unsigned char lds_e[2][CS_N * 2 * KTC * 16];  // 2 x 17408
  __shared__ unsigned long long rowkey[RPB];
  __shared__ int cand[CAND_CAP];
  __shared__ int cand_n;
  __shared__ float lsum;

  const int t = threadIdx.x;             // 256
  const int w = t >> 6, l = t & 63;
  const int grp = l >> 5;
  const int lane31 = l & 31;
  const int n0 = blockIdx.x * RPB;       // 512 blocks
  const int bi = n0 >> 12;
  const int hw0 = n0 & 4095;
  const int myhw = hw0 + w * 32 + lane31;

  if (t < RPB) rowkey[t] = ~0ull;
  if (t == 0){ cand_n = 0; lsum = 0.f; }

  // ---- z fragments (B operand): z[c][myhw] in VGPRs; 17th slice = (1,0,..)
  bf16x8 ah0[16], ahx;
  {
    const float* zb = feats + (size_t)bi * CC * HW + myhw;
    #pragma unroll
    for (int cs = 0; cs < 16; ++cs){
      #pragma unroll
      for (int j = 0; j < 8; ++j)
        ah0[cs][j] = (short)bf16rn(zb[(size_t)(cs * 16 + grp * 8 + j) * HW]);
    }
    #pragma unroll
    for (int j = 0; j < 8; ++j) ahx[j] = 0;
    if (grp == 0) ahx[0] = (short)0x3F80;   // bf16(1.0)
  }

  const unsigned short* ehg = (const unsigned short*)(out + EH_OFF);
  const unsigned short* exg = (const unsigned short*)(out + EXT_OFF);

  // full rounds: chunk ix = i*256+t (i<4); tail: ix = 1024+t (t<64, ee-slice)
  int ofs_[4];
  #pragma unroll
  for (int i = 0; i < 4; ++i){
    int ix = i * 256 + t;
    int cd = ix & 31, g = (ix >> 5) & 1, cs = ix >> 6;
    ofs_[i] = cd * CC + cs * 16 + g * 8;
  }

#define STAGE(KT, B) { \
    const unsigned short* tb_ = ehg + (size_t)(KT) * (KTC * CC); \
    _Pragma("unroll") \
    for (int i_ = 0; i_ < 4; ++i_) \
      gload16(tb_ + ofs_[i_], &lds_e[B][(i_ * 256 + t) * 16]); \
    if (t < 64){ \
      int cd_ = t & 31, g_ = (t >> 5) & 1; \
      gload16(exg + ((size_t)((KT) * KTC + cd_) * 16 + g_ * 8), \
              &lds_e[B][(1024 + t) * 16]); \
    } }

#define COMPUTE(B) { \
    _Pragma("unroll") \
    for (int ii = 0; ii < 16; ++ii){ accA[ii] = 0.f; accB[ii] = 0.f; } \
    _Pragma("unroll") \
    for (int cs = 0; cs < 16; ++cs){ \
      const unsigned char* bp_ = &lds_e[B][(size_t)(cs * 2 + grp) * 512 + lane31 * 16]; \
      bf16x8 e_ = *(const bf16x8*)(bp_); \
      if (cs & 1) accB = __builtin_amdgcn_mfma_f32_32x32x16_bf16(e_, ah0[cs], accB, 0, 0, 0); \
      else        accA = __builtin_amdgcn_mfma_f32_32x32x16_bf16(e_, ah0[cs], accA, 0, 0, 0); \
    } \
    { \
      const unsigned char* bp_ = &lds_e[B][(size_t)(16 * 2 + grp) * 512 + lane31 * 16]; \
      bf16x8 e_ = *(const bf16x8*)(bp_); \
      accA = __builtin_amdgcn_mfma_f32_32x32x16_bf16(e_, ahx, accA, 0, 0, 0); \
    } }

  f32x16 accA, accB;
  float m0 = 3e38f, ss0 = 0.f, inv0 = 0.f;

  STAGE(0, 0);
  __syncthreads();

  // fused loop: kt<64 = stats pass, kt>=64 = probs+cand pass
  for (int kt = 0; kt < 2 * KT_N; ++kt){
    const int tt = kt & 63;
    const int buf = kt & 1;
    if (kt < 2 * KT_N - 1) STAGE((kt + 1) & 63, buf ^ 1);
    COMPUTE(buf);
    if (kt < KT_N){
      #pragma unroll
      for (int r = 0; r < 16; ++r){
        float s = -2.f * (accA[r] + accB[r]);
        m0 = fminf(m0, s);
        ss0 += __expf(-s);                  // s in [-1,1]: shift-free
      }
      if (kt == KT_N - 1){
        m0 = fminf(m0, __shfl_xor(m0, 32));
        ss0 += __shfl_xor(ss0, 32);
        inv0 = 1.f / ss0;
      }
    } else {
      float* pb = out + (size_t)PROBS_OFF
                + (size_t)(bi * KK + tt * KTC + 4 * grp) * HW + myhw;
      #pragma unroll
      for (int r = 0; r < 16; ++r){
        int off = (r & 3) + 8 * (r >> 2);
        float s = -2.f * (accA[r] + accB[r]);
        pb[(size_t)off * HW] = __expf(-s) * inv0;
        if (s <= m0 + TAU){
          int sl = atomicAdd(&cand_n, 1);
          if (sl < CAND_CAP)
            cand[sl] = ((w * 32 + lane31) << 16) | (tt * KTC + 4 * grp + off);
        }
      }
    }
    __syncthreads();
  }

  // ---- bit-exact rescore of candidates (numpy fp32 chain), first-min wins
  int nc = cand_n; if (nc > CAND_CAP) nc = CAND_CAP;
  for (int i = t; i < nc; i += 256){
    int rc = cand[i];
    int rl = rc >> 16, code = rc & 0xffff;
    int n = n0 + rl;
    const float* zp = feats + (size_t)(n >> 12) * CC * HW + (n & 4095);
    const float* ep = cb + (size_t)code * CC;
    float a = 0.f;
    #pragma unroll 8
    for (int c = 0; c < CC; ++c) a = __builtin_fmaf(zp[(size_t)c * HW], ep[c], a);
    float t1 = __fadd_rn(out[ZZ_OFF + n], out[EE_OFF + code]);
    float d = __fadd_rn(t1, -2.f * a);
    unsigned long long key = ((unsigned long long)__float_as_uint(d) << 32) | (unsigned)code;
    atomicMin(&rowkey[rl], key);
  }
  __syncthreads();

  if (t < RPB) out[IDX_OFF + n0 + t] = (float)(int)(rowkey[t] & 0xffffffffu);

  // ---- loss: threads 0..127 each handle one row
  if (t < RPB){
    int code = (int)(rowkey[t] & 0xffffffffu);
    const float* ep = cb + (size_t)code * CC;
    const float* zp = feats + (size_t)bi * CC * HW + hw0 + t;
    float s = 0.f;
    for (int c = 0; c < CC; ++c){
      float dz = ep[c] - zp[(size_t)c * HW];
      s = __builtin_fmaf(dz, dz, s);
    }
    atomicAdd(&lsum, s);
  }
  __syncthreads();
  if (t == 0) atomicAdd(out + LOSS_OFF, lsum * (1.25f / 16777216.f));
}

// ---------------- z_q gather (bit-exact copy; overwrites scratch) ----------------
__global__ void k_zq(const float* __restrict__ cb, float* __restrict__ out){
  const int f4 = blockIdx.x * 256 + threadIdx.x;  // 16384 blocks
  const int f = f4 * 4;
  const int b = f >> 20;
  const int rem = f & 1048575;
  const int c = rem >> 12;
  const int hw = rem & 4095;
  const int n = b * HW + hw;
  const float* idxf = out + IDX_OFF;
  float4 iv = *(const float4*)(idxf + n);
  float4 o;
  o.x = cb[(size_t)((int)iv.x) * CC + c];
  o.y = cb[(size_t)((int)iv.y) * CC + c];
  o.z = cb[(size_t)((int)iv.z) * CC + c];
  o.w = cb[(size_t)((int)iv.w) * CC + c];
  *(float4*)(out + f) = o;
}

extern "C" void kernel_launch(void* const* d_in, const int* in_sizes, int n_in,
                              void* d_out, int out_size, void* d_ws, size_t ws_size,
                              hipStream_t stream){
  const float* feats = (const float*)d_in[0];
  const float* cb    = (const float*)d_in[1];
  float* out = (float*)d_out;

  (void)hipMemsetAsync(out + LOSS_OFF, 0, sizeof(float), stream);
  hipLaunchKernelGGL(k_prep2, dim3(8),     dim3(256), 0, stream, cb, out);
  hipLaunchKernelGGL(k_zz,    dim3(256),   dim3(256), 0, stream, feats, out);
  hipLaunchKernelGGL(k_mfma,  dim3(512),   dim3(256), 0, stream, feats, cb, out);
  hipLaunchKernelGGL(k_zq,    dim3(16384), dim3(256), 0, stream, cb, out);
}

// Round 14
// 534.354 us; speedup vs baseline: 1.0009x; 1.0009x over previous
//
#include <hip/hip_runtime.h>

#define HW 4096
#define CC 256
#define KK 2048
#define BB 16
#define NN (BB*HW)          // 65536
#define RPB 128             // rows per block

// d_out layout (floats): [z_q 16777216][idx 65536][loss 1][probs 134217728]
#define ZQ_SZ   (BB*CC*HW)
#define IDX_OFF ZQ_SZ
#define LOSS_OFF (IDX_OFF + NN)
#define PROBS_OFF (LOSS_OFF + 1)

// scratch parked in z_q region (float offsets), overwritten by k_zq at the end
#define EH_OFF 0            // eh[K][C] bf16 (rn) = 262144 floats
#define EE_OFF 262144       // ee_np[K] f32
#define EXT_OFF 264192      // eext[K][16] bf16 (ee-channel block)
#define ZZ_OFF 280576       // zz_np[N] f32
#define MS_OFF 346112       // m partial [2][N] f32
#define SS_OFF 477184       // sum partial [2][N] f32
#define IKEY_OFF 608256     // u64 idxkey[N] = 131072 floats

#define TAU 0.01f
#define CAND_CAP 512
#define KTC 32              // codes per k-tile
#define KT_N 32             // tiles per half (1024 codes)
#define CS_N 17             // 16 c-slices + ee-slice

typedef short bf16x8 __attribute__((ext_vector_type(8)));
typedef float f32x16 __attribute__((ext_vector_type(16)));
typedef unsigned int u32;
typedef unsigned long long u64;

__device__ __forceinline__ void gload16(const void* g, void* l){
  __builtin_amdgcn_global_load_lds(
      (const __attribute__((address_space(1))) u32*)g,
      (__attribute__((address_space(3))) u32*)l, 16, 0, 0);
}

__device__ __forceinline__ unsigned short bf16rn(float x){
  unsigned u = __float_as_uint(x);
  return (unsigned short)((u + 0x7fffu + ((u >> 16) & 1u)) >> 16);
}

// ---- numpy pairwise sum-of-squares over 256 elems (PW_BLOCKSIZE=128) ----
template<int STRIDE>
__device__ __forceinline__ float np_sumsq256(const float* __restrict__ a){
  float res0 = 0.f, res1 = 0.f;
  #pragma unroll
  for (int h = 0; h < 2; h++){
    const float* p = a + (size_t)h * 128 * STRIDE;
    float r[8];
    #pragma unroll
    for (int j = 0; j < 8; j++){ float x = p[(size_t)j * STRIDE]; r[j] = __fmul_rn(x, x); }
    for (int i = 8; i < 128; i += 8){
      #pragma unroll
      for (int j = 0; j < 8; j++){
        float x = p[(size_t)(i + j) * STRIDE];
        r[j] = __fadd_rn(r[j], __fmul_rn(x, x));
      }
    }
    float s = __fadd_rn(__fadd_rn(__fadd_rn(r[0], r[1]), __fadd_rn(r[2], r[3])),
                        __fadd_rn(__fadd_rn(r[4], r[5]), __fadd_rn(r[6], r[7])));
    if (h == 0) res0 = s; else res1 = s;
  }
  return __fadd_rn(res0, res1);
}

// ---------------- prep: bf16(rn) codebook + np-exact ee + ee-channel ----------------
__global__ void k_prep2(const float* __restrict__ cb, float* __restrict__ out){
  const int k = blockIdx.x * 256 + threadIdx.x;   // 8 blocks
  unsigned short* eh = (unsigned short*)(out + EH_OFF);
  unsigned short* ex = (unsigned short*)(out + EXT_OFF);
  const float* row = cb + (size_t)k * CC;
  for (int c = 0; c < CC; c++) eh[k * CC + c] = bf16rn(row[c]);
  float ee = np_sumsq256<1>(row);
  out[EE_OFF + k] = ee;
  ex[k * 16] = bf16rn(-0.5f * ee);
  #pragma unroll
  for (int j = 1; j < 16; ++j) ex[k * 16 + j] = 0;
}

// ---------------- zz[n] = np-pairwise sum_c feats^2 ----------------
__global__ void k_zz(const float* __restrict__ feats, float* __restrict__ out){
  const int n = blockIdx.x * 256 + threadIdx.x;   // 256 blocks
  const int b = n >> 12, hw = n & 4095;
  out[ZZ_OFF + n] = np_sumsq256<HW>(feats + (size_t)b * CC * HW + hw);
}

// ======== shared machinery for the two GEMM kernels (4 waves, 256 thr) ========
// block bid: rb = bid>>1 (128 rows), h = bid&1 (1024-code half)
// lds_e[buf][cs 17][grp 2][code 32][16B]; mfma(e, z) -> D[code][zrow]

#define GEMM_PROLOG \
  const int t = threadIdx.x; \
  const int w = t >> 6, l = t & 63; \
  const int grp = l >> 5; \
  const int lane31 = l & 31; \
  const int bid = blockIdx.x; \
  const int rb = bid >> 1, h = bid & 1; \
  const int n0 = rb * RPB; \
  const int bi = n0 >> 12; \
  const int hw0 = n0 & 4095; \
  const int myhw = hw0 + w * 32 + lane31; \
  bf16x8 ah0[16], ahx; \
  { \
    const float* zb = feats + (size_t)bi * CC * HW + myhw; \
    _Pragma("unroll") \
    for (int cs = 0; cs < 16; ++cs){ \
      _Pragma("unroll") \
      for (int j = 0; j < 8; ++j) \
        ah0[cs][j] = (short)bf16rn(zb[(size_t)(cs * 16 + grp * 8 + j) * HW]); \
    } \
    _Pragma("unroll") \
    for (int j = 0; j < 8; ++j) ahx[j] = 0; \
    if (grp == 0) ahx[0] = (short)0x3F80; \
  } \
  const unsigned short* ehg = (const unsigned short*)(out + EH_OFF) + (size_t)h * 1024 * CC; \
  const unsigned short* exg = (const unsigned short*)(out + EXT_OFF) + (size_t)h * 1024 * 16; \
  int ofs_[4]; \
  _Pragma("unroll") \
  for (int i = 0; i < 4; ++i){ \
    int ix = i * 256 + t; \
    int cd = ix & 31, g = (ix >> 5) & 1, cs = ix >> 6; \
    ofs_[i] = cd * CC + cs * 16 + g * 8; \
  } \
  int x_ofs = 0; \
  if (t < 64){ int cd = t & 31, g = (t >> 5) & 1; x_ofs = cd * 16 + g * 8; }

#define STAGE(KT, B) { \
    const size_t kto_ = (size_t)(KT) * (KTC * CC); \
    _Pragma("unroll") \
    for (int i_ = 0; i_ < 4; ++i_) \
      gload16(ehg + ofs_[i_] + kto_, &lds_e[B][(i_ * 256 + t) * 16]); \
    if (t < 64) \
      gload16(exg + x_ofs + (size_t)(KT) * (KTC * 16), &lds_e[B][(1024 + t) * 16]); }

#define COMPUTE(B) { \
    _Pragma("unroll") \
    for (int ii = 0; ii < 16; ++ii){ accA[ii] = 0.f; accB[ii] = 0.f; } \
    _Pragma("unroll") \
    for (int cs = 0; cs < 16; ++cs){ \
      const unsigned char* bp_ = &lds_e[B][(size_t)(cs * 2 + grp) * 512 + lane31 * 16]; \
      bf16x8 e_ = *(const bf16x8*)(bp_); \
      if (cs & 1) accB = __builtin_amdgcn_mfma_f32_32x32x16_bf16(e_, ah0[cs], accB, 0, 0, 0); \
      else        accA = __builtin_amdgcn_mfma_f32_32x32x16_bf16(e_, ah0[cs], accA, 0, 0, 0); \
    } \
    { \
      const unsigned char* bp_ = &lds_e[B][(size_t)(32 + grp) * 512 + lane31 * 16]; \
      bf16x8 e_ = *(const bf16x8*)(bp_); \
      accA = __builtin_amdgcn_mfma_f32_32x32x16_bf16(e_, ahx, accA, 0, 0, 0); \
    } }

// ---------------- pass 1: per-(row, half) stats ----------------
__global__ __launch_bounds__(256, 4)
void k_stats(const float* __restrict__ feats, float* __restrict__ out){
  __shared__ __align__(16) unsigned char lds_e[2][CS_N * 2 * KTC * 16];  // 34816 B
  GEMM_PROLOG
  f32x16 accA, accB;
  float m0 = 3e38f, ss0 = 0.f;

  STAGE(0, 0);
  __syncthreads();
  for (int kt = 0; kt < KT_N; ++kt){
    const int buf = kt & 1;
    if (kt < KT_N - 1) STAGE(kt + 1, buf ^ 1);
    COMPUTE(buf);
    #pragma unroll
    for (int r = 0; r < 16; ++r){
      float s = -2.f * (accA[r] + accB[r]);
      m0 = fminf(m0, s);
      ss0 += __expf(-s);                 // s in [-1,1]: shift-free
    }
    __syncthreads();
  }
  m0 = fminf(m0, __shfl_xor(m0, 32));
  ss0 += __shfl_xor(ss0, 32);
  if (grp == 0){
    out[MS_OFF + h * NN + n0 + w * 32 + lane31] = m0;
    out[SS_OFF + h * NN + n0 + w * 32 + lane31] = ss0;
  }
}

// ---------------- pass 2: probs + candidates + bit-exact rescore ----------------
__global__ __launch_bounds__(256, 4)
void k_probs(const float* __restrict__ feats, const float* __restrict__ cb,
             float* __restrict__ out){
  __shared__ __align__(16) unsigned char lds_e[2][CS_N * 2 * KTC * 16];
  __shared__ int cand[CAND_CAP];
  __shared__ int cand_n;
  GEMM_PROLOG
  if (t == 0) cand_n = 0;
  f32x16 accA, accB;

  // merged stats for my row
  const int myrow = n0 + w * 32 + lane31;
  float m0, inv0;
  {
    float ma = out[MS_OFF + myrow], mb = out[MS_OFF + NN + myrow];
    float sa = out[SS_OFF + myrow], sb = out[SS_OFF + NN + myrow];
    m0 = fminf(ma, mb);
    inv0 = 1.f / (sa + sb);
  }

  STAGE(0, 0);
  __syncthreads();
  for (int kt = 0; kt < KT_N; ++kt){
    const int buf = kt & 1;
    if (kt < KT_N - 1) STAGE(kt + 1, buf ^ 1);
    COMPUTE(buf);
    float* pb = out + (size_t)PROBS_OFF
              + (size_t)(bi * KK + h * 1024 + kt * KTC + 4 * grp) * HW + myhw;
    #pragma unroll
    for (int r = 0; r < 16; ++r){
      int off = (r & 3) + 8 * (r >> 2);
      float s = -2.f * (accA[r] + accB[r]);
      pb[(size_t)off * HW] = __expf(-s) * inv0;
      if (s <= m0 + TAU){
        int sl = atomicAdd(&cand_n, 1);
        if (sl < CAND_CAP)
          cand[sl] = ((w * 32 + lane31) << 16) | (h * 1024 + kt * KTC + 4 * grp + off);
      }
    }
    __syncthreads();
  }

  // bit-exact rescore (numpy fp32 chain) -> global first-min key
  u64* ikey = (u64*)(out + IKEY_OFF);
  int nc = cand_n; if (nc > CAND_CAP) nc = CAND_CAP;
  for (int i = t; i < nc; i += 256){
    int rc = cand[i];
    int rl = (rc >> 16) & 127, code = rc & 2047;
    int n = n0 + rl;
    const float* zp = feats + (size_t)(n >> 12) * CC * HW + (n & 4095);
    const float* ep = cb + (size_t)code * CC;
    float a = 0.f;
    #pragma unroll 8
    for (int c = 0; c < CC; ++c) a = __builtin_fmaf(zp[(size_t)c * HW], ep[c], a);
    float t1 = __fadd_rn(out[ZZ_OFF + n], out[EE_OFF + code]);
    float d = __fadd_rn(t1, -2.f * a);
    u64 key = ((u64)__float_as_uint(d) << 32) | (unsigned)code;
    atomicMin(&ikey[n], key);
  }
}

// ---------------- final: idx + loss ----------------
__global__ void k_final(const float* __restrict__ feats, const float* __restrict__ cb,
                        float* __restrict__ out){
  const int t = threadIdx.x;
  const int n = blockIdx.x * 256 + t;    // 256 blocks
  const u64* ikey = (const u64*)(out + IKEY_OFF);
  int code = (int)(ikey[n] & 2047u);
  out[IDX_OFF + n] = (float)code;
  const int bi = n >> 12, hw = n & 4095;
  const float* ep = cb + (size_t)code * CC;
  const float* zp = feats + (size_t)bi * CC * HW + hw;
  float s = 0.f;
  for (int c = 0; c < CC; ++c){
    float dz = ep[c] - zp[(size_t)c * HW];
    s = __builtin_fmaf(dz, dz, s);
  }
  #pragma unroll
  for (int off = 32; off; off >>= 1) s += __shfl_xor(s, off);
  if ((t & 63) == 0) atomicAdd(out + LOSS_OFF, s * (1.25f / 16777216.f));
}

// ---------------- z_q gather (bit-exact copy; overwrites scratch) ----------------
__global__ void k_zq(const float* __restrict__ cb, float* __restrict__ out){
  const int f4 = blockIdx.x * 256 + threadIdx.x;  // 16384 blocks
  const int f = f4 * 4;
  const int b = f >> 20;
  const int rem = f & 1048575;
  const int c = rem >> 12;
  const int hw = rem & 4095;
  const int n = b * HW + hw;
  const float* idxf = out + IDX_OFF;
  float4 iv = *(const float4*)(idxf + n);
  float4 o;
  o.x = cb[(size_t)((int)iv.x) * CC + c];
  o.y = cb[(size_t)((int)iv.y) * CC + c];
  o.z = cb[(size_t)((int)iv.z) * CC + c];
  o.w = cb[(size_t)((int)iv.w) * CC + c];
  *(float4*)(out + f) = o;
}

extern "C" void kernel_launch(void* const* d_in, const int* in_sizes, int n_in,
                              void* d_out, int out_size, void* d_ws, size_t ws_size,
                              hipStream_t stream){
  const float* feats = (const float*)d_in[0];
  const float* cb    = (const float*)d_in[1];
  float* out = (float*)d_out;

  (void)hipMemsetAsync(out + LOSS_OFF, 0, sizeof(float), stream);
  (void)hipMemsetAsync(out + IKEY_OFF, 0xFF, (size_t)NN * 8, stream);
  hipLaunchKernelGGL(k_prep2, dim3(8),     dim3(256), 0, stream, cb, out);
  hipLaunchKernelGGL(k_zz,    dim3(256),   dim3(256), 0, stream, feats, out);
  hipLaunchKernelGGL(k_stats, dim3(1024),  dim3(256), 0, stream, feats, out);
  hipLaunchKernelGGL(k_probs, dim3(1024),  dim3(256), 0, stream, feats, cb, out);
  hipLaunchKernelGGL(k_final, dim3(256),   dim3(256), 0, stream, feats, cb, out);
  hipLaunchKernelGGL(k_zq,    dim3(16384), dim3(256), 0, stream, cb, out);
}

// Round 16
// 517.480 us; speedup vs baseline: 1.0335x; 1.0326x over previous
//
#include <hip/hip_runtime.h>

#define HW 4096
#define CC 256
#define KK 2048
#define BB 16
#define NN (BB*HW)          // 65536
#define RPB 128             // rows per block

// d_out layout (floats): [z_q 16777216][idx 65536][loss 1][probs 134217728]
#define ZQ_SZ   (BB*CC*HW)
#define IDX_OFF ZQ_SZ
#define LOSS_OFF (IDX_OFF + NN)
#define PROBS_OFF (LOSS_OFF + 1)

// scratch parked in z_q region (float offsets), overwritten by k_zq at the end
#define EH_OFF 0            // eh[K][C] bf16 (rn) = 262144 floats
#define EE_OFF 262144       // ee_np[K] f32
#define EXT_OFF 264192      // eext[K][16] bf16 (ee-channel block)
#define ZZ_OFF 280576       // zz_np[N] f32
#define MS_OFF 346112       // m partial [2][N] f32
#define SS_OFF 477184       // sum partial [2][N] f32
#define IKEY_OFF 608256     // u64 idxkey[N]

#define TAU 0.01f
#define CAND_CAP 512
#define KTC 32              // codes per k-tile
#define KT_N 32             // tiles per half (1024 codes)
#define CS_N 17             // 16 c-slices + ee-slice
#define HB 17408            // bytes per tile

typedef short bf16x8 __attribute__((ext_vector_type(8)));
typedef float f32x16 __attribute__((ext_vector_type(16)));
typedef unsigned int u32;
typedef unsigned long long u64;

__device__ __forceinline__ void gload16(const void* g, void* l){
  __builtin_amdgcn_global_load_lds(
      (const __attribute__((address_space(1))) u32*)g,
      (__attribute__((address_space(3))) u32*)l, 16, 0, 0);
}

__device__ __forceinline__ unsigned short bf16rn(float x){
  unsigned u = __float_as_uint(x);
  return (unsigned short)((u + 0x7fffu + ((u >> 16) & 1u)) >> 16);
}

// counted-vmcnt barrier: leave N newest VMEM ops in flight (wave-uniform branch)
#define PB(n0, n1) { \
  if (t < 64) asm volatile("s_waitcnt vmcnt(" n0 ")\n\ts_barrier" ::: "memory"); \
  else        asm volatile("s_waitcnt vmcnt(" n1 ")\n\ts_barrier" ::: "memory"); }

// ---- numpy pairwise sum-of-squares over 256 elems (PW_BLOCKSIZE=128) ----
template<int STRIDE>
__device__ __forceinline__ float np_sumsq256(const float* __restrict__ a){
  float res0 = 0.f, res1 = 0.f;
  #pragma unroll
  for (int h = 0; h < 2; h++){
    const float* p = a + (size_t)h * 128 * STRIDE;
    float r[8];
    #pragma unroll
    for (int j = 0; j < 8; j++){ float x = p[(size_t)j * STRIDE]; r[j] = __fmul_rn(x, x); }
    for (int i = 8; i < 128; i += 8){
      #pragma unroll
      for (int j = 0; j < 8; j++){
        float x = p[(size_t)(i + j) * STRIDE];
        r[j] = __fadd_rn(r[j], __fmul_rn(x, x));
      }
    }
    float s = __fadd_rn(__fadd_rn(__fadd_rn(r[0], r[1]), __fadd_rn(r[2], r[3])),
                        __fadd_rn(__fadd_rn(r[4], r[5]), __fadd_rn(r[6], r[7])));
    if (h == 0) res0 = s; else res1 = s;
  }
  return __fadd_rn(res0, res1);
}

// ---------------- bf16(rn) conversion, coalesced ----------------
__global__ void k_cvt(const float* __restrict__ cb, float* __restrict__ out){
  const int i = blockIdx.x * 256 + threadIdx.x;   // 256 blocks; 8 channels each
  const int k = i >> 5, c8 = (i & 31) * 8;
  const float* row = cb + (size_t)k * CC + c8;
  unsigned short v[8];
  #pragma unroll
  for (int j = 0; j < 8; ++j) v[j] = bf16rn(row[j]);
  *(uint4*)((unsigned short*)(out + EH_OFF) + (size_t)k * CC + c8) = *(uint4*)v;
}

// ---------------- ee (np-exact) + ee-channel block ----------------
__global__ void k_ee(const float* __restrict__ cb, float* __restrict__ out){
  const int k = blockIdx.x * 256 + threadIdx.x;   // 8 blocks
  unsigned short* ex = (unsigned short*)(out + EXT_OFF);
  float ee = np_sumsq256<1>(cb + (size_t)k * CC);
  out[EE_OFF + k] = ee;
  ex[k * 16] = bf16rn(-0.5f * ee);
  #pragma unroll
  for (int j = 1; j < 16; ++j) ex[k * 16 + j] = 0;
}

// ---------------- zz[n] = np-pairwise sum_c feats^2 ----------------
__global__ void k_zz(const float* __restrict__ feats, float* __restrict__ out){
  const int n = blockIdx.x * 256 + threadIdx.x;   // 256 blocks
  const int b = n >> 12, hw = n & 4095;
  out[ZZ_OFF + n] = np_sumsq256<HW>(feats + (size_t)b * CC * HW + hw);
}

// ======== shared machinery for the two GEMM kernels (4 waves, 256 thr) ========
// block bid: rb = bid>>1 (128 rows), h = bid&1 (1024-code half)
// tile layout [cs 17][grp 2][code 32][16B]; mfma(e, z) -> D[code][zrow]

#define GEMM_PROLOG \
  const int t = threadIdx.x; \
  const int w = t >> 6, l = t & 63; \
  const int grp = l >> 5; \
  const int lane31 = l & 31; \
  const int bid = blockIdx.x; \
  const int rb = bid >> 1, h = bid & 1; \
  const int n0 = rb * RPB; \
  const int bi = n0 >> 12; \
  const int hw0 = n0 & 4095; \
  const int myhw = hw0 + w * 32 + lane31; \
  bf16x8 ah0[16], ahx; \
  { \
    const float* zb = feats + (size_t)bi * CC * HW + myhw; \
    _Pragma("unroll") \
    for (int cs = 0; cs < 16; ++cs){ \
      _Pragma("unroll") \
      for (int j = 0; j < 8; ++j) \
        ah0[cs][j] = (short)bf16rn(zb[(size_t)(cs * 16 + grp * 8 + j) * HW]); \
    } \
    _Pragma("unroll") \
    for (int j = 0; j < 8; ++j) ahx[j] = 0; \
    if (grp == 0) ahx[0] = (short)0x3F80; \
  } \
  const unsigned short* ehg = (const unsigned short*)(out + EH_OFF) + (size_t)h * 1024 * CC; \
  const unsigned short* exg = (const unsigned short*)(out + EXT_OFF) + (size_t)h * 1024 * 16; \
  int ofs_[4]; \
  _Pragma("unroll") \
  for (int i = 0; i < 4; ++i){ \
    int ix = i * 256 + t; \
    int cd = ix & 31, g = (ix >> 5) & 1, cs = ix >> 6; \
    ofs_[i] = cd * CC + cs * 16 + g * 8; \
  } \
  int x_ofs = 0; \
  if (t < 64){ int cd = t & 31, g = (t >> 5) & 1; x_ofs = cd * 16 + g * 8; }

#define STAGE(KT, BI) { \
    unsigned char* bb_ = lds_e + (size_t)(BI) * HB; \
    const size_t kto_ = (size_t)(KT) * (KTC * CC); \
    _Pragma("unroll") \
    for (int i_ = 0; i_ < 4; ++i_) \
      gload16(ehg + ofs_[i_] + kto_, bb_ + (i_ * 256 + t) * 16); \
    if (t < 64) \
      gload16(exg + x_ofs + (size_t)(KT) * (KTC * 16), bb_ + (1024 + t) * 16); }

#define COMPUTE(BI) { \
    const unsigned char* hb_ = lds_e + (size_t)(BI) * HB; \
    _Pragma("unroll") \
    for (int ii = 0; ii < 16; ++ii){ accA[ii] = 0.f; accB[ii] = 0.f; } \
    _Pragma("unroll") \
    for (int cs = 0; cs < 16; ++cs){ \
      const unsigned char* bp_ = hb_ + (size_t)(cs * 2 + grp) * 512 + lane31 * 16; \
      bf16x8 e_ = *(const bf16x8*)(bp_); \
      if (cs & 1) accB = __builtin_amdgcn_mfma_f32_32x32x16_bf16(e_, ah0[cs], accB, 0, 0, 0); \
      else        accA = __builtin_amdgcn_mfma_f32_32x32x16_bf16(e_, ah0[cs], accA, 0, 0, 0); \
    } \
    { \
      const unsigned char* bp_ = hb_ + (size_t)(32 + grp) * 512 + lane31 * 16; \
      bf16x8 e_ = *(const bf16x8*)(bp_); \
      accA = __builtin_amdgcn_mfma_f32_32x32x16_bf16(e_, ahx, accA, 0, 0, 0); \
    } }

// ---------------- pass 1: per-(row, half) stats; 3-buf counted-vmcnt pipeline ----------------
__global__ __launch_bounds__(256, 3)
void k_stats(const float* __restrict__ feats, float* __restrict__ out){
  __shared__ __align__(16) unsigned char lds_e[3 * HB];   // 52224 B
  GEMM_PROLOG
  f32x16 accA, accB;
  float m0 = 3e38f, ss0 = 0.f;

  STAGE(0, 0);
  STAGE(1, 1);
  PB("5", "4")                      // retire tile-0 loads; tile-1 stays in flight

  int cur = 0, nxt = 2;
  for (int kt = 0; kt < KT_N; ++kt){
    if (kt + 2 < KT_N) STAGE(kt + 2, nxt);
    COMPUTE(cur);
    #pragma unroll
    for (int r = 0; r < 16; ++r){
      float s = -2.f * (accA[r] + accB[r]);
      m0 = fminf(m0, s);
      ss0 += __expf(-s);            // s in [-1,1]: shift-free
    }
    cur = cur == 2 ? 0 : cur + 1;
    nxt = nxt == 2 ? 0 : nxt + 1;
    if (kt == KT_N - 1) break;      // no trailing barrier
    if (kt < KT_N - 2){ PB("5", "4") } else { PB("0", "0") }
  }
  m0 = fminf(m0, __shfl_xor(m0, 32));
  ss0 += __shfl_xor(ss0, 32);
  if (grp == 0){
    out[MS_OFF + h * NN + n0 + w * 32 + lane31] = m0;
    out[SS_OFF + h * NN + n0 + w * 32 + lane31] = ss0;
  }
}

// ---------------- pass 2: probs + candidates + bit-exact rescore ----------------
__global__ __launch_bounds__(256, 2)
void k_probs(const float* __restrict__ feats, const float* __restrict__ cb,
             float* __restrict__ out){
  __shared__ __align__(16) unsigned char lds_e[3 * HB];
  __shared__ int cand[CAND_CAP];
  __shared__ int cand_n;
  GEMM_PROLOG
  if (t == 0) cand_n = 0;
  f32x16 accA, accB;

  // merged stats for my row
  const int myrow = n0 + w * 32 + lane31;
  float m0, inv0;
  {
    float ma = out[MS_OFF + myrow], mb = out[MS_OFF + NN + myrow];
    float sa = out[SS_OFF + myrow], sb = out[SS_OFF + NN + myrow];
    m0 = fminf(ma, mb);
    inv0 = 1.f / (sa + sb);
  }

  STAGE(0, 0);
  STAGE(1, 1);
  PB("5", "4")

  int cur = 0, nxt = 2;
  for (int kt = 0; kt < KT_N; ++kt){
    if (kt + 2 < KT_N) STAGE(kt + 2, nxt);
    COMPUTE(cur);
    float* pb = out + (size_t)PROBS_OFF
              + (size_t)(bi * KK + h * 1024 + kt * KTC + 4 * grp) * HW + myhw;
    #pragma unroll
    for (int r = 0; r < 16; ++r){
      int off = (r & 3) + 8 * (r >> 2);
      float s = -2.f * (accA[r] + accB[r]);
      pb[(size_t)off * HW] = __expf(-s) * inv0;
      if (s <= m0 + TAU){
        int sl = atomicAdd(&cand_n, 1);
        if (sl < CAND_CAP)
          cand[sl] = ((w * 32 + lane31) << 16) | (h * 1024 + kt * KTC + 4 * grp + off);
      }
    }
    cur = cur == 2 ? 0 : cur + 1;
    nxt = nxt == 2 ? 0 : nxt + 1;
    if (kt == KT_N - 1) break;
    // FIFO: [gl(kt+1)] [st(kt-1)] [gl(kt+2)] [st(kt)] -> retire gl(kt+1) only
    if (kt == 0)            { PB("21", "20") }
    else if (kt < KT_N - 2) { PB("37", "36") }
    else                    { PB("16", "16") }
  }
  __syncthreads();   // full drain before cross-wave cand read

  // bit-exact rescore (numpy fp32 chain) -> global first-min key
  u64* ikey = (u64*)(out + IKEY_OFF);
  int nc = cand_n; if (nc > CAND_CAP) nc = CAND_CAP;
  for (int i = t; i < nc; i += 256){
    int rc = cand[i];
    int rl = (rc >> 16) & 127, code = rc & 2047;
    int n = n0 + rl;
    const float* zp = feats + (size_t)(n >> 12) * CC * HW + (n & 4095);
    const float* ep = cb + (size_t)code * CC;
    float a = 0.f;
    #pragma unroll 8
    for (int c = 0; c < CC; ++c) a = __builtin_fmaf(zp[(size_t)c * HW], ep[c], a);
    float t1 = __fadd_rn(out[ZZ_OFF + n], out[EE_OFF + code]);
    float d = __fadd_rn(t1, -2.f * a);
    u64 key = ((u64)__float_as_uint(d) << 32) | (unsigned)code;
    atomicMin(&ikey[n], key);
  }
}

// ---------------- final: idx + loss ----------------
__global__ void k_final(const float* __restrict__ feats, const float* __restrict__ cb,
                        float* __restrict__ out){
  const int t = threadIdx.x;
  const int n = blockIdx.x * 256 + t;    // 256 blocks
  const u64* ikey = (const u64*)(out + IKEY_OFF);
  int code = (int)(ikey[n] & 2047u);
  out[IDX_OFF + n] = (float)code;
  const int bi = n >> 12, hw = n & 4095;
  const float* ep = cb + (size_t)code * CC;
  const float* zp = feats + (size_t)bi * CC * HW + hw;
  float s = 0.f;
  for (int c = 0; c < CC; ++c){
    float dz = ep[c] - zp[(size_t)c * HW];
    s = __builtin_fmaf(dz, dz, s);
  }
  #pragma unroll
  for (int off = 32; off; off >>= 1) s += __shfl_xor(s, off);
  if ((t & 63) == 0) atomicAdd(out + LOSS_OFF, s * (1.25f / 16777216.f));
}

// ---------------- z_q gather (bit-exact copy; overwrites scratch) ----------------
__global__ void k_zq(const float* __restrict__ cb, float* __restrict__ out){
  const int f4 = blockIdx.x * 256 + threadIdx.x;  // 16384 blocks
  const int f = f4 * 4;
  const int b = f >> 20;
  const int rem = f & 1048575;
  const int c = rem >> 12;
  const int hw = rem & 4095;
  const int n = b * HW + hw;
  const float* idxf = out + IDX_OFF;
  float4 iv = *(const float4*)(idxf + n);
  float4 o;
  o.x = cb[(size_t)((int)iv.x) * CC + c];
  o.y = cb[(size_t)((int)iv.y) * CC + c];
  o.z = cb[(size_t)((int)iv.z) * CC + c];
  o.w = cb[(size_t)((int)iv.w) * CC + c];
  *(float4*)(out + f) = o;
}

extern "C" void kernel_launch(void* const* d_in, const int* in_sizes, int n_in,
                              void* d_out, int out_size, void* d_ws, size_t ws_size,
                              hipStream_t stream){
  const float* feats = (const float*)d_in[0];
  const float* cb    = (const float*)d_in[1];
  float* out = (float*)d_out;

  (void)hipMemsetAsync(out + LOSS_OFF, 0, sizeof(float), stream);
  (void)hipMemsetAsync(out + IKEY_OFF, 0xFF, (size_t)NN * 8, stream);
  hipLaunchKernelGGL(k_cvt,   dim3(256),   dim3(256), 0, stream, cb, out);
  hipLaunchKernelGGL(k_ee,    dim3(8),     dim3(256), 0, stream, cb, out);
  hipLaunchKernelGGL(k_zz,    dim3(256),   dim3(256), 0, stream, feats, out);
  hipLaunchKernelGGL(k_stats, dim3(1024),  dim3(256), 0, stream, feats, out);
  hipLaunchKernelGGL(k_probs, dim3(1024),  dim3(256), 0, stream, feats, cb, out);
  hipLaunchKernelGGL(k_final, dim3(256),   dim3(256), 0, stream, feats, cb, out);
  hipLaunchKernelGGL(k_zq,    dim3(16384), dim3(256), 0, stream, cb, out);
}

// Round 17
// 517.166 us; speedup vs baseline: 1.0342x; 1.0006x over previous
//
#include <hip/hip_runtime.h>

#define HW 4096
#define CC 256
#define KK 2048
#define BB 16
#define NN (BB*HW)          // 65536
#define RPB 256             // rows per block (2 rowsets x 4 waves x 32)

// d_out layout (floats): [z_q 16777216][idx 65536][loss 1][probs 134217728]
#define ZQ_SZ   (BB*CC*HW)
#define IDX_OFF ZQ_SZ
#define LOSS_OFF (IDX_OFF + NN)
#define PROBS_OFF (LOSS_OFF + 1)

// scratch parked in z_q region (float offsets), overwritten by k_zq at the end
#define EH_OFF 0            // eh[K][C] bf16 (rn) = 262144 floats
#define EE_OFF 262144       // ee_np[K] f32
#define EXT_OFF 264192      // eext[K][16] bf16 (ee-channel block)
#define MS_OFF 346112       // m partial [2][N] f32
#define SS_OFF 477184       // sum partial [2][N] f32
#define IKEY_OFF 608256     // u64 idxkey[N]

#define TAU 0.01f
#define CAND_CAP 512
#define KTC 32              // codes per k-tile
#define KT_N 32             // tiles per half (1024 codes)
#define HB 17408            // bytes per tile: 17 cs * 2 grp * 32 code * 16B

typedef short bf16x8 __attribute__((ext_vector_type(8)));
typedef float f32x16 __attribute__((ext_vector_type(16)));
typedef unsigned int u32;
typedef unsigned long long u64;

__device__ __forceinline__ void gload16(const void* g, void* l){
  __builtin_amdgcn_global_load_lds(
      (const __attribute__((address_space(1))) u32*)g,
      (__attribute__((address_space(3))) u32*)l, 16, 0, 0);
}

__device__ __forceinline__ unsigned short bf16rn(float x){
  unsigned u = __float_as_uint(x);
  return (unsigned short)((u + 0x7fffu + ((u >> 16) & 1u)) >> 16);
}

// counted-vmcnt barrier: leave N newest VMEM ops in flight (wave-uniform branch)
#define PB(n0, n1) { \
  if (t < 64) asm volatile("s_waitcnt vmcnt(" n0 ")\n\ts_barrier" ::: "memory"); \
  else        asm volatile("s_waitcnt vmcnt(" n1 ")\n\ts_barrier" ::: "memory"); }

// ---- numpy pairwise sum-of-squares over 256 elems (PW_BLOCKSIZE=128) ----
template<int STRIDE>
__device__ __forceinline__ float np_sumsq256(const float* __restrict__ a){
  float res0 = 0.f, res1 = 0.f;
  #pragma unroll
  for (int h = 0; h < 2; h++){
    const float* p = a + (size_t)h * 128 * STRIDE;
    float r[8];
    #pragma unroll
    for (int j = 0; j < 8; j++){ float x = p[(size_t)j * STRIDE]; r[j] = __fmul_rn(x, x); }
    for (int i = 8; i < 128; i += 8){
      #pragma unroll
      for (int j = 0; j < 8; j++){
        float x = p[(size_t)(i + j) * STRIDE];
        r[j] = __fadd_rn(r[j], __fmul_rn(x, x));
      }
    }
    float s = __fadd_rn(__fadd_rn(__fadd_rn(r[0], r[1]), __fadd_rn(r[2], r[3])),
                        __fadd_rn(__fadd_rn(r[4], r[5]), __fadd_rn(r[6], r[7])));
    if (h == 0) res0 = s; else res1 = s;
  }
  return __fadd_rn(res0, res1);
}

// ---------------- bf16(rn) conversion, coalesced ----------------
__global__ void k_cvt(const float* __restrict__ cb, float* __restrict__ out){
  const int i = blockIdx.x * 256 + threadIdx.x;   // 256 blocks; 8 channels each
  const int k = i >> 5, c8 = (i & 31) * 8;
  const float* row = cb + (size_t)k * CC + c8;
  unsigned short v[8];
  #pragma unroll
  for (int j = 0; j < 8; ++j) v[j] = bf16rn(row[j]);
  *(uint4*)((unsigned short*)(out + EH_OFF) + (size_t)k * CC + c8) = *(uint4*)v;
}

// ---------------- ee (np-exact) + ee-channel block ----------------
__global__ void k_ee(const float* __restrict__ cb, float* __restrict__ out){
  const int k = blockIdx.x * 256 + threadIdx.x;   // 8 blocks
  unsigned short* ex = (unsigned short*)(out + EXT_OFF);
  float ee = np_sumsq256<1>(cb + (size_t)k * CC);
  out[EE_OFF + k] = ee;
  ex[k * 16] = bf16rn(-0.5f * ee);
  #pragma unroll
  for (int j = 1; j < 16; ++j) ex[k * 16 + j] = 0;
}

// ======== shared machinery (4 waves, 256 thr, 2 rowsets/wave) ========
// block bid: rb = bid>>1 (256 rows), h = bid&1 (1024-code half)
// tile layout [cs 17][grp 2][code 32][16B]; mfma(e, z) -> D[code][zrow]

#define GEMM_PROLOG \
  const int t = threadIdx.x; \
  const int w = t >> 6, l = t & 63; \
  const int grp = l >> 5; \
  const int lane31 = l & 31; \
  const int bid = blockIdx.x; \
  const int rb = bid >> 1, h = bid & 1; \
  const int n0 = rb * RPB; \
  const int bi = n0 >> 12; \
  const int hw0 = n0 & 4095; \
  const int hwA = hw0 + w * 64 + lane31; \
  bf16x8 ahA[16], ahB[16], ahx; \
  { \
    const float* zb = feats + (size_t)bi * CC * HW + hwA; \
    _Pragma("unroll") \
    for (int cs = 0; cs < 16; ++cs){ \
      _Pragma("unroll") \
      for (int j = 0; j < 8; ++j){ \
        size_t co = (size_t)(cs * 16 + grp * 8 + j) * HW; \
        ahA[cs][j] = (short)bf16rn(zb[co]); \
        ahB[cs][j] = (short)bf16rn(zb[co + 32]); \
      } \
    } \
    _Pragma("unroll") \
    for (int j = 0; j < 8; ++j) ahx[j] = 0; \
    if (grp == 0) ahx[0] = (short)0x3F80; \
  } \
  const unsigned short* ehg = (const unsigned short*)(out + EH_OFF) + (size_t)h * 1024 * CC; \
  const unsigned short* exg = (const unsigned short*)(out + EXT_OFF) + (size_t)h * 1024 * 16; \
  int ofs_[4]; \
  _Pragma("unroll") \
  for (int i = 0; i < 4; ++i){ \
    int ix = i * 256 + t; \
    int cd = ix & 31, g = (ix >> 5) & 1, cs = ix >> 6; \
    ofs_[i] = cd * CC + cs * 16 + g * 8; \
  } \
  int x_ofs = 0; \
  if (t < 64){ int cd = t & 31, g = (t >> 5) & 1; x_ofs = cd * 16 + g * 8; }

#define STAGE(KT, BI) { \
    unsigned char* bb_ = lds_e + (size_t)(BI) * HB; \
    const size_t kto_ = (size_t)(KT) * (KTC * CC); \
    _Pragma("unroll") \
    for (int i_ = 0; i_ < 4; ++i_) \
      gload16(ehg + ofs_[i_] + kto_, bb_ + (i_ * 256 + t) * 16); \
    if (t < 64) \
      gload16(exg + x_ofs + (size_t)(KT) * (KTC * 16), bb_ + (1024 + t) * 16); }

// 17 ds_reads feed 34 MFMAs across 4 independent chains
#define COMPUTE(BI) { \
    const unsigned char* hb_ = lds_e + (size_t)(BI) * HB; \
    _Pragma("unroll") \
    for (int ii = 0; ii < 16; ++ii){ a00[ii]=0.f; a01[ii]=0.f; a10[ii]=0.f; a11[ii]=0.f; } \
    _Pragma("unroll") \
    for (int cs = 0; cs < 16; ++cs){ \
      const unsigned char* bp_ = hb_ + (size_t)(cs * 2 + grp) * 512 + lane31 * 16; \
      bf16x8 e_ = *(const bf16x8*)(bp_); \
      if (cs & 1){ \
        a01 = __builtin_amdgcn_mfma_f32_32x32x16_bf16(e_, ahA[cs], a01, 0, 0, 0); \
        a11 = __builtin_amdgcn_mfma_f32_32x32x16_bf16(e_, ahB[cs], a11, 0, 0, 0); \
      } else { \
        a00 = __builtin_amdgcn_mfma_f32_32x32x16_bf16(e_, ahA[cs], a00, 0, 0, 0); \
        a10 = __builtin_amdgcn_mfma_f32_32x32x16_bf16(e_, ahB[cs], a10, 0, 0, 0); \
      } \
    } \
    { \
      const unsigned char* bp_ = hb_ + (size_t)(32 + grp) * 512 + lane31 * 16; \
      bf16x8 e_ = *(const bf16x8*)(bp_); \
      a00 = __builtin_amdgcn_mfma_f32_32x32x16_bf16(e_, ahx, a00, 0, 0, 0); \
      a10 = __builtin_amdgcn_mfma_f32_32x32x16_bf16(e_, ahx, a10, 0, 0, 0); \
    } }

// ---------------- pass 1: per-(row, half) stats ----------------
__global__ __launch_bounds__(256, 2)
void k_stats(const float* __restrict__ feats, float* __restrict__ out){
  __shared__ __align__(16) unsigned char lds_e[3 * HB];   // 52224 B
  GEMM_PROLOG
  f32x16 a00, a01, a10, a11;
  float mA = 3e38f, sA = 0.f, mB = 3e38f, sB = 0.f;

  STAGE(0, 0);
  STAGE(1, 1);
  PB("5", "4")

  int cur = 0, nxt = 2;
  for (int kt = 0; kt < KT_N; ++kt){
    if (kt + 2 < KT_N) STAGE(kt + 2, nxt);
    COMPUTE(cur);
    #pragma unroll
    for (int r = 0; r < 16; ++r){
      float s0 = -2.f * (a00[r] + a01[r]);
      float s1 = -2.f * (a10[r] + a11[r]);
      mA = fminf(mA, s0); sA += __expf(-s0);
      mB = fminf(mB, s1); sB += __expf(-s1);
    }
    cur = cur == 2 ? 0 : cur + 1;
    nxt = nxt == 2 ? 0 : nxt + 1;
    if (kt == KT_N - 1) break;
    if (kt < KT_N - 2){ PB("5", "4") } else { PB("0", "0") }
  }
  mA = fminf(mA, __shfl_xor(mA, 32)); sA += __shfl_xor(sA, 32);
  mB = fminf(mB, __shfl_xor(mB, 32)); sB += __shfl_xor(sB, 32);
  if (grp == 0){
    int r0 = n0 + w * 64 + lane31;
    out[MS_OFF + h * NN + r0]      = mA;
    out[SS_OFF + h * NN + r0]      = sA;
    out[MS_OFF + h * NN + r0 + 32] = mB;
    out[SS_OFF + h * NN + r0 + 32] = sB;
  }
}

// ---------------- pass 2: probs + candidates + bit-exact rescore ----------------
__global__ __launch_bounds__(256, 2)
void k_probs(const float* __restrict__ feats, const float* __restrict__ cb,
             float* __restrict__ out){
  __shared__ __align__(16) unsigned char lds_e[3 * HB];
  __shared__ int cand[CAND_CAP];
  __shared__ int cand_n;
  GEMM_PROLOG
  if (t == 0) cand_n = 0;
  f32x16 a00, a01, a10, a11;

  // merged stats for my two rows
  const int myrowA = n0 + w * 64 + lane31;
  float m0A, inv0A, m0B, inv0B;
  {
    float ma = out[MS_OFF + myrowA], mb = out[MS_OFF + NN + myrowA];
    float sa = out[SS_OFF + myrowA], sb = out[SS_OFF + NN + myrowA];
    m0A = fminf(ma, mb); inv0A = 1.f / (sa + sb);
    ma = out[MS_OFF + myrowA + 32]; mb = out[MS_OFF + NN + myrowA + 32];
    sa = out[SS_OFF + myrowA + 32]; sb = out[SS_OFF + NN + myrowA + 32];
    m0B = fminf(ma, mb); inv0B = 1.f / (sa + sb);
  }

  STAGE(0, 0);
  STAGE(1, 1);
  PB("5", "4")

  int cur = 0, nxt = 2;
  for (int kt = 0; kt < KT_N; ++kt){
    if (kt + 2 < KT_N) STAGE(kt + 2, nxt);
    COMPUTE(cur);
    float* pb = out + (size_t)PROBS_OFF
              + (size_t)(bi * KK + h * 1024 + kt * KTC + 4 * grp) * HW + hwA;
    #pragma unroll
    for (int r = 0; r < 16; ++r){
      int off = (r & 3) + 8 * (r >> 2);
      float s0 = -2.f * (a00[r] + a01[r]);
      float s1 = -2.f * (a10[r] + a11[r]);
      float* p = pb + (size_t)off * HW;
      p[0]  = __expf(-s0) * inv0A;
      p[32] = __expf(-s1) * inv0B;
      int cg = h * 1024 + kt * KTC + 4 * grp + off;
      if (s0 <= m0A + TAU){
        int sl = atomicAdd(&cand_n, 1);
        if (sl < CAND_CAP) cand[sl] = ((w * 64 + lane31) << 16) | cg;
      }
      if (s1 <= m0B + TAU){
        int sl = atomicAdd(&cand_n, 1);
        if (sl < CAND_CAP) cand[sl] = ((w * 64 + 32 + lane31) << 16) | cg;
      }
    }
    cur = cur == 2 ? 0 : cur + 1;
    nxt = nxt == 2 ? 0 : nxt + 1;
    if (kt == KT_N - 1) break;
    if (kt == 0){ PB("37", "36") } else { PB("63", "63") }
  }
  __syncthreads();   // full drain before cross-wave cand read

  // bit-exact rescore (numpy fp32 chain, zz on demand) -> global first-min key
  u64* ikey = (u64*)(out + IKEY_OFF);
  int nc = cand_n; if (nc > CAND_CAP) nc = CAND_CAP;
  for (int i = t; i < nc; i += 256){
    int rc = cand[i];
    int rl = (rc >> 16) & 255, code = rc & 2047;
    int n = n0 + rl;
    const float* zp = feats + (size_t)(n >> 12) * CC * HW + (n & 4095);
    const float* ep = cb + (size_t)code * CC;
    float a = 0.f;
    #pragma unroll 8
    for (int c = 0; c < CC; ++c) a = __builtin_fmaf(zp[(size_t)c * HW], ep[c], a);
    float zzv = np_sumsq256<HW>(zp);
    float t1 = __fadd_rn(zzv, out[EE_OFF + code]);
    float d = __fadd_rn(t1, -2.f * a);
    u64 key = ((u64)__float_as_uint(d) << 32) | (unsigned)code;
    atomicMin(&ikey[n], key);
  }
}

// ---------------- final: idx + loss ----------------
__global__ void k_final(const float* __restrict__ feats, const float* __restrict__ cb,
                        float* __restrict__ out){
  const int t = threadIdx.x;
  const int n = blockIdx.x * 256 + t;    // 256 blocks
  const u64* ikey = (const u64*)(out + IKEY_OFF);
  int code = (int)(ikey[n] & 2047u);
  out[IDX_OFF + n] = (float)code;
  const int bi = n >> 12, hw = n & 4095;
  const float* ep = cb + (size_t)code * CC;
  const float* zp = feats + (size_t)bi * CC * HW + hw;
  float s = 0.f;
  for (int c = 0; c < CC; ++c){
    float dz = ep[c] - zp[(size_t)c * HW];
    s = __builtin_fmaf(dz, dz, s);
  }
  #pragma unroll
  for (int off = 32; off; off >>= 1) s += __shfl_xor(s, off);
  if ((t & 63) == 0) atomicAdd(out + LOSS_OFF, s * (1.25f / 16777216.f));
}

// ---------------- z_q gather (bit-exact copy; overwrites scratch) ----------------
__global__ void k_zq(const float* __restrict__ cb, float* __restrict__ out){
  const int f4 = blockIdx.x * 256 + threadIdx.x;  // 16384 blocks
  const int f = f4 * 4;
  const int b = f >> 20;
  const int rem = f & 1048575;
  const int c = rem >> 12;
  const int hw = rem & 4095;
  const int n = b * HW + hw;
  const float* idxf = out + IDX_OFF;
  float4 iv = *(const float4*)(idxf + n);
  float4 o;
  o.x = cb[(size_t)((int)iv.x) * CC + c];
  o.y = cb[(size_t)((int)iv.y) * CC + c];
  o.z = cb[(size_t)((int)iv.z) * CC + c];
  o.w = cb[(size_t)((int)iv.w) * CC + c];
  *(float4*)(out + f) = o;
}

extern "C" void kernel_launch(void* const* d_in, const int* in_sizes, int n_in,
                              void* d_out, int out_size, void* d_ws, size_t ws_size,
                              hipStream_t stream){
  const float* feats = (const float*)d_in[0];
  const float* cb    = (const float*)d_in[1];
  float* out = (float*)d_out;

  (void)hipMemsetAsync(out + LOSS_OFF, 0, sizeof(float), stream);
  (void)hipMemsetAsync(out + IKEY_OFF, 0xFF, (size_t)NN * 8, stream);
  hipLaunchKernelGGL(k_cvt,   dim3(256),   dim3(256), 0, stream, cb, out);
  hipLaunchKernelGGL(k_ee,    dim3(8),     dim3(256), 0, stream, cb, out);
  hipLaunchKernelGGL(k_stats, dim3(512),   dim3(256), 0, stream, feats, out);
  hipLaunchKernelGGL(k_probs, dim3(512),   dim3(256), 0, stream, feats, cb, out);
  hipLaunchKernelGGL(k_final, dim3(256),   dim3(256), 0, stream, feats, cb, out);
  hipLaunchKernelGGL(k_zq,    dim3(16384), dim3(256), 0, stream, cb, out);
}

// Round 18
// 459.776 us; speedup vs baseline: 1.1632x; 1.1248x over previous
//
#include <hip/hip_runtime.h>

#define HW 4096
#define CC 256
#define KK 2048
#define BB 16
#define NN (BB*HW)          // 65536
#define RPB 128             // rows per block

// d_out layout (floats): [z_q 16777216][idx 65536][loss 1][probs 134217728]
#define ZQ_SZ   (BB*CC*HW)
#define IDX_OFF ZQ_SZ
#define LOSS_OFF (IDX_OFF + NN)
#define PROBS_OFF (LOSS_OFF + 1)

// scratch parked in z_q region (float offsets), overwritten by k_zq at the end
#define EH_OFF 0            // eh[K][C] bf16 (rn) = 262144 floats
#define EE_OFF 262144       // ee_np[K] f32

#define TAU 0.01f
#define CAND_CAP 512
#define KTC 64              // codes per k-tile
#define KT_N 32             // tiles per pass

typedef short bf16x8 __attribute__((ext_vector_type(8)));
typedef float f32x16 __attribute__((ext_vector_type(16)));
typedef unsigned int u32;
typedef unsigned long long u64;

__device__ __forceinline__ void gload16(const void* g, void* l){
  __builtin_amdgcn_global_load_lds(
      (const __attribute__((address_space(1))) u32*)g,
      (__attribute__((address_space(3))) u32*)l, 16, 0, 0);
}

__device__ __forceinline__ unsigned short bf16rn(float x){
  unsigned u = __float_as_uint(x);
  return (unsigned short)((u + 0x7fffu + ((u >> 16) & 1u)) >> 16);
}

// ---- numpy pairwise sum-of-squares over 256 elems (PW_BLOCKSIZE=128) ----
template<int STRIDE>
__device__ __forceinline__ float np_sumsq256(const float* __restrict__ a){
  float res0 = 0.f, res1 = 0.f;
  #pragma unroll
  for (int h = 0; h < 2; h++){
    const float* p = a + (size_t)h * 128 * STRIDE;
    float r[8];
    #pragma unroll
    for (int j = 0; j < 8; j++){ float x = p[(size_t)j * STRIDE]; r[j] = __fmul_rn(x, x); }
    for (int i = 8; i < 128; i += 8){
      #pragma unroll
      for (int j = 0; j < 8; j++){
        float x = p[(size_t)(i + j) * STRIDE];
        r[j] = __fadd_rn(r[j], __fmul_rn(x, x));
      }
    }
    float s = __fadd_rn(__fadd_rn(__fadd_rn(r[0], r[1]), __fadd_rn(r[2], r[3])),
                        __fadd_rn(__fadd_rn(r[4], r[5]), __fadd_rn(r[6], r[7])));
    if (h == 0) res0 = s; else res1 = s;
  }
  return __fadd_rn(res0, res1);
}

// ---------------- bf16(rn) conversion, coalesced ----------------
__global__ void k_cvt(const float* __restrict__ cb, float* __restrict__ out){
  const int i = blockIdx.x * 256 + threadIdx.x;   // 256 blocks; 8 channels each
  const int k = i >> 5, c8 = (i & 31) * 8;
  const float* row = cb + (size_t)k * CC + c8;
  unsigned short v[8];
  #pragma unroll
  for (int j = 0; j < 8; ++j) v[j] = bf16rn(row[j]);
  *(uint4*)((unsigned short*)(out + EH_OFF) + (size_t)k * CC + c8) = *(uint4*)v;
}

// ---------------- ee[k] = np-exact sum of squares ----------------
__global__ void k_ee(const float* __restrict__ cb, float* __restrict__ out){
  const int k = blockIdx.x * 256 + threadIdx.x;   // 8 blocks
  out[EE_OFF + k] = np_sumsq256<1>(cb + (size_t)k * CC);
}

// ---------------- main fused MFMA kernel: 128 rows x 2048 codes, 512 blocks ----------------
// lds_e[buf][cs 16][grp 2][code 64][16B]; mfma(e, z) -> D[code][zrow]
// Deferred POST: iteration kt runs POST(kt-1) (VALU) alongside COMPUTE(kt) (MFMA).
__global__ __launch_bounds__(256, 2)
void k_mfma(const float* __restrict__ feats, const float* __restrict__ cb,
            float* __restrict__ out){
  __shared__ __align__(16) unsigned char lds_e[2][32768];
  __shared__ float ee_lds[KK];
  __shared__ unsigned long long rowkey[RPB];
  __shared__ int cand[CAND_CAP];
  __shared__ int cand_n;
  __shared__ float lsum;

  const int t = threadIdx.x;             // 256
  const int w = t >> 6, l = t & 63;
  const int grp = l >> 5;
  const int lane31 = l & 31;
  const int n0 = blockIdx.x * RPB;       // 512 blocks
  const int bi = n0 >> 12;
  const int hw0 = n0 & 4095;
  const int myhw = hw0 + w * 32 + lane31;

  for (int i = t; i < KK; i += 256) ee_lds[i] = out[EE_OFF + i];
  if (t < RPB) rowkey[t] = ~0ull;
  if (t == 0){ cand_n = 0; lsum = 0.f; }

  // ---- z fragments (B operand): z[c][myhw], resident in VGPRs
  bf16x8 ah0[16];
  {
    const float* zb = feats + (size_t)bi * CC * HW + myhw;
    #pragma unroll
    for (int cs = 0; cs < 16; ++cs){
      #pragma unroll
      for (int j = 0; j < 8; ++j)
        ah0[cs][j] = (short)bf16rn(zb[(size_t)(cs * 16 + grp * 8 + j) * HW]);
    }
  }

  const unsigned short* ehg = (const unsigned short*)(out + EH_OFF);

  // per-thread source element offsets for the 8 staging chunks (32KB tile)
  int ofs_[8];
  #pragma unroll
  for (int i = 0; i < 8; ++i){
    int ix = i * 256 + t;
    int cd = ix & 63, g = (ix >> 6) & 1, cs = ix >> 7;
    ofs_[i] = cd * CC + cs * 16 + g * 8;
  }

#define STAGE(KT, B) { \
    const unsigned short* tb_ = ehg + (size_t)(KT) * (KTC * CC); \
    _Pragma("unroll") \
    for (int i_ = 0; i_ < 8; ++i_) \
      gload16(tb_ + ofs_[i_], &lds_e[B][(i_ * 256 + t) * 16]); }

#define COMPUTE(B, AA, AB) { \
    _Pragma("unroll") \
    for (int ii = 0; ii < 16; ++ii){ AA[ii] = 0.f; AB[ii] = 0.f; } \
    _Pragma("unroll") \
    for (int cs = 0; cs < 16; ++cs){ \
      const unsigned char* bp_ = &lds_e[B][(size_t)(cs * 2 + grp) * 1024 + lane31 * 16]; \
      bf16x8 e0_ = *(const bf16x8*)(bp_); \
      bf16x8 e1_ = *(const bf16x8*)(bp_ + 512); \
      AA = __builtin_amdgcn_mfma_f32_32x32x16_bf16(e0_, ah0[cs], AA, 0, 0, 0); \
      AB = __builtin_amdgcn_mfma_f32_32x32x16_bf16(e1_, ah0[cs], AB, 0, 0, 0); \
    } }

// POST of tile PKT using register set (PA,PB_); stats if PKT<32 else probs+cand
#define POST(PKT, PA, PB_) { \
    const int ptt = (PKT) & 31; \
    const int eebase = ptt * 64 + 4 * grp; \
    if ((PKT) < KT_N){ \
      _Pragma("unroll") \
      for (int r = 0; r < 16; ++r){ \
        int off = (r & 3) + 8 * (r >> 2); \
        float s0 = ee_lds[eebase + off]      - 2.f * PA[r]; \
        float s1 = ee_lds[eebase + off + 32] - 2.f * PB_[r]; \
        m0 = fminf(m0, fminf(s0, s1)); \
        ss0 += __expf(-s0) + __expf(-s1); \
      } \
    } else { \
      float* pb = out + (size_t)PROBS_OFF \
                + (size_t)(bi * KK + ptt * 64 + 4 * grp) * HW + myhw; \
      _Pragma("unroll") \
      for (int r = 0; r < 16; ++r){ \
        int off = (r & 3) + 8 * (r >> 2); \
        float s0 = ee_lds[eebase + off]      - 2.f * PA[r]; \
        float s1 = ee_lds[eebase + off + 32] - 2.f * PB_[r]; \
        float* p = pb + (size_t)off * HW; \
        p[0]               = __expf(-s0) * inv0; \
        p[(size_t)32 * HW] = __expf(-s1) * inv0; \
        int cg = eebase + off; \
        if (s0 <= m0 + TAU){ \
          int sl = atomicAdd(&cand_n, 1); \
          if (sl < CAND_CAP) cand[sl] = ((w * 32 + lane31) << 16) | cg; \
        } \
        if (s1 <= m0 + TAU){ \
          int sl = atomicAdd(&cand_n, 1); \
          if (sl < CAND_CAP) cand[sl] = ((w * 32 + lane31) << 16) | (cg + 32); \
        } \
      } \
    } }

  f32x16 aA0, aB0, aA1, aB1;
  float m0 = 3e38f, ss0 = 0.f, inv0 = 0.f;

  STAGE(0, 0);
  __syncthreads();

  // fused loop, 2x-unrolled so accumulator-set selection is compile-time
  for (int kt2 = 0; kt2 < KT_N; ++kt2){
    const int ktA = 2 * kt2;          // even step: compute set0, post set1
    {
      STAGE((ktA + 1) & 31, 1);       // buf = ktA&1 = 0 -> stage into 1
      if (ktA > 0) POST(ktA - 1, aA1, aB1);
      if (ktA == KT_N){               // after POST(31): finalize stats
        m0 = fminf(m0, __shfl_xor(m0, 32));
        ss0 += __shfl_xor(ss0, 32);
        inv0 = 1.f / ss0;
      }
      COMPUTE(0, aA0, aB0);
      __syncthreads();
    }
    {
      const int ktB = ktA + 1;        // odd step: compute set1, post set0
      if (ktB < 2 * KT_N - 1) STAGE((ktB + 1) & 31, 0);
      POST(ktB - 1, aA0, aB0);
      COMPUTE(1, aA1, aB1);
      __syncthreads();
    }
  }
  POST(2 * KT_N - 1, aA1, aB1);       // tile 63 (probs)
  __syncthreads();

  // ---- bit-exact rescore of candidates (numpy fp32 chain, zz on demand)
  int nc = cand_n; if (nc > CAND_CAP) nc = CAND_CAP;
  for (int i = t; i < nc; i += 256){
    int rc = cand[i];
    int rl = (rc >> 16) & 127, code = rc & 2047;
    int n = n0 + rl;
    const float* zp = feats + (size_t)(n >> 12) * CC * HW + (n & 4095);
    const float* ep = cb + (size_t)code * CC;
    float a = 0.f;
    #pragma unroll 8
    for (int c = 0; c < CC; ++c) a = __builtin_fmaf(zp[(size_t)c * HW], ep[c], a);
    float zzv = np_sumsq256<HW>(zp);
    float t1 = __fadd_rn(zzv, ee_lds[code]);
    float d = __fadd_rn(t1, -2.f * a);
    unsigned long long key = ((unsigned long long)__float_as_uint(d) << 32) | (unsigned)code;
    atomicMin(&rowkey[rl], key);
  }
  __syncthreads();

  if (t < RPB) out[IDX_OFF + n0 + t] = (float)(int)(rowkey[t] & 2047u);

  // ---- loss: threads 0..127 each handle one row
  if (t < RPB){
    int code = (int)(rowkey[t] & 2047u);
    const float* ep = cb + (size_t)code * CC;
    const float* zp = feats + (size_t)bi * CC * HW + hw0 + t;
    float s = 0.f;
    for (int c = 0; c < CC; ++c){
      float dz = ep[c] - zp[(size_t)c * HW];
      s = __builtin_fmaf(dz, dz, s);
    }
    atomicAdd(&lsum, s);
  }
  __syncthreads();
  if (t == 0) atomicAdd(out + LOSS_OFF, lsum * (1.25f / 16777216.f));
}

// ---------------- z_q gather (bit-exact copy; overwrites scratch) ----------------
__global__ void k_zq(const float* __restrict__ cb, float* __restrict__ out){
  const int f4 = blockIdx.x * 256 + threadIdx.x;  // 16384 blocks
  const int f = f4 * 4;
  const int b = f >> 20;
  const int rem = f & 1048575;
  const int c = rem >> 12;
  const int hw = rem & 4095;
  const int n = b * HW + hw;
  const float* idxf = out + IDX_OFF;
  float4 iv = *(const float4*)(idxf + n);
  float4 o;
  o.x = cb[(size_t)((int)iv.x) * CC + c];
  o.y = cb[(size_t)((int)iv.y) * CC + c];
  o.z = cb[(size_t)((int)iv.z) * CC + c];
  o.w = cb[(size_t)((int)iv.w) * CC + c];
  *(float4*)(out + f) = o;
}

extern "C" void kernel_launch(void* const* d_in, const int* in_sizes, int n_in,
                              void* d_out, int out_size, void* d_ws, size_t ws_size,
                              hipStream_t stream){
  const float* feats = (const float*)d_in[0];
  const float* cb    = (const float*)d_in[1];
  float* out = (float*)d_out;

  (void)hipMemsetAsync(out + LOSS_OFF, 0, sizeof(float), stream);
  hipLaunchKernelGGL(k_cvt,  dim3(256),   dim3(256), 0, stream, cb, out);
  hipLaunchKernelGGL(k_ee,   dim3(8),     dim3(256), 0, stream, cb, out);
  hipLaunchKernelGGL(k_mfma, dim3(512),   dim3(256), 0, stream, feats, cb, out);
  hipLaunchKernelGGL(k_zq,   dim3(16384), dim3(256), 0, stream, cb, out);
}